// Round 7
// baseline (104.276 us; speedup 1.0000x reference)
//
#include <hip/hip_runtime.h>

#define NN 32
#define CC 256
#define HH 56
#define WW 56
#define HWSZ 3136            // 56*56
#define QPP 784              // float4 quads per spatial plane (3136/4)
#define NQ 25088             // quads over N*HW = 32*784
#define NHW 100352           // 32*3136
#define NGRP 8               // channel groups in pool (32 ch each)
#define CPGRP 32
#define ABLK 8               // channel blocks in apply (32 ch each)

typedef float v4f __attribute__((ext_vector_type(4)));

__device__ __forceinline__ float4 f4max(float4 a, float4 b) {
    float4 r;
    r.x = fmaxf(a.x, b.x); r.y = fmaxf(a.y, b.y);
    r.z = fmaxf(a.z, b.z); r.w = fmaxf(a.w, b.w);
    return r;
}
__device__ __forceinline__ float4 f4add(float4 a, float4 b) {
    float4 r;
    r.x = a.x + b.x; r.y = a.y + b.y; r.z = a.z + b.z; r.w = a.w + b.w;
    return r;
}

// ---------------- K1a: pool partials, linear-stream layout ----------------
// 784 blocks x 256. thread <-> (group, n, hwq); loops 32 channels.
// Per (n,group): one strictly sequential 400 KB read stream (copy-like).
__global__ __launch_bounds__(256) void k_pool_lin(const float* __restrict__ x,
                                                  float* __restrict__ pmaxp,
                                                  float* __restrict__ psump,
                                                  float* __restrict__ stats) {
    if (blockIdx.x == 0 && threadIdx.x == 0) {
        stats[0] = 0.f;
        stats[1] = 0.f;
    }
    const int gid = blockIdx.x * 256 + threadIdx.x;  // 0..NGRP*NQ-1
    const int grp = gid / NQ;
    const int r = gid - grp * NQ;                    // n*QPP + hwq
    const int n = r / QPP;
    const int hwq = r - n * QPP;

    const float4* p = (const float4*)x + (size_t)(n * CC + grp * CPGRP) * QPP + hwq;
    float4 v0 = p[0];
    float4 vmax = v0, vsum = v0;
#pragma unroll 8
    for (int i = 1; i < CPGRP; ++i) {
        float4 v = p[(size_t)i * QPP];
        vmax = f4max(vmax, v);
        vsum = f4add(vsum, v);
    }
    ((float4*)pmaxp)[(size_t)grp * NQ + r] = vmax;
    ((float4*)psump)[(size_t)grp * NQ + r] = vsum;
}

// ---------------- K1b: merge NGRP partials -> pool [N,2,HW] ----------------
__global__ __launch_bounds__(256) void k_merge(const float* __restrict__ pmaxp,
                                               const float* __restrict__ psump,
                                               float* __restrict__ pool) {
    const int q = blockIdx.x * 256 + threadIdx.x;   // 0..NQ-1
    if (q >= NQ) return;
    float4 m = ((const float4*)pmaxp)[q];
    float4 s = ((const float4*)psump)[q];
#pragma unroll
    for (int g = 1; g < NGRP; ++g) {
        m = f4max(m, ((const float4*)pmaxp)[(size_t)g * NQ + q]);
        s = f4add(s, ((const float4*)psump)[(size_t)g * NQ + q]);
    }
    const int n = q / QPP;
    const int hwq = q - n * QPP;
    ((float4*)pool)[(size_t)n * 2 * QPP + hwq] = m;
    float4 mean;
    mean.x = s.x * 0.00390625f; mean.y = s.y * 0.00390625f;
    mean.z = s.z * 0.00390625f; mean.w = s.w * 0.00390625f;
    ((float4*)pool)[(size_t)n * 2 * QPP + QPP + hwq] = mean;
}

// ---------------- K2: 5x5 conv (2->1 ch, SAME) + BN stat partials ----------
__global__ __launch_bounds__(256) void k_conv(const float* __restrict__ pool,
                                              const float* __restrict__ cw,
                                              float* __restrict__ conv,
                                              float* __restrict__ stats) {
    __shared__ float w[50];
    const int tid = threadIdx.x;
    if (tid < 50) w[tid] = cw[tid];
    __syncthreads();

    const int gid = blockIdx.x * 256 + tid;   // 0..NHW-1
    const int n = gid / HWSZ;
    const int hw = gid - n * HWSZ;
    const int h = hw / WW;
    const int wc = hw - h * WW;

    const float* pb = pool + (size_t)n * 2 * HWSZ;
    float acc = 0.f;
#pragma unroll
    for (int ci = 0; ci < 2; ++ci)
#pragma unroll
        for (int kh = 0; kh < 5; ++kh) {
            const int hh = h + kh - 2;
            if (hh < 0 || hh >= HH) continue;
#pragma unroll
            for (int kw = 0; kw < 5; ++kw) {
                const int wwc = wc + kw - 2;
                if (wwc < 0 || wwc >= WW) continue;
                acc += pb[ci * HWSZ + hh * WW + wwc] * w[ci * 25 + kh * 5 + kw];
            }
        }
    conv[gid] = acc;

    float s = acc, s2 = acc * acc;
#pragma unroll
    for (int i = 1; i < 64; i <<= 1) {
        s += __shfl_xor(s, i);
        s2 += __shfl_xor(s2, i);
    }
    if ((tid & 63) == 0) {
        atomicAdd(&stats[0], s);
        atomicAdd(&stats[1], s2);
    }
}

// ---------------- K3: fused BN + double-sigmoid gate + apply ---------------
// 784 blocks x 256. thread <-> (n, cblk-of-32, hwq); gate computed once,
// reused over 32 channels; linear read/write streams per (n,cblk).
__global__ __launch_bounds__(256) void k_apply(const float* __restrict__ x,
                                               const float* __restrict__ conv,
                                               const float* __restrict__ stats,
                                               const float* __restrict__ gamma,
                                               const float* __restrict__ beta,
                                               float* __restrict__ out) {
    const float invM = 1.f / (float)NHW;
    const float mean = stats[0] * invM;
    const float var = stats[1] * invM - mean * mean;
    const float scale = rsqrtf(var + 1e-5f) * gamma[0];
    const float shift = beta[0] - mean * scale;

    const int gid = blockIdx.x * 256 + threadIdx.x;  // 0..NN*ABLK*QPP-1
    const int v = gid / QPP;          // n*ABLK + cblk
    const int hwq = gid - v * QPP;
    const int cblk = v & (ABLK - 1);
    const int n = v >> 3;

    const float4 cv = ((const float4*)conv)[n * QPP + hwq];
    float4 g;
    {
        float t = cv.x * scale + shift;
        float s1 = 1.f / (1.f + __expf(-t));
        g.x = 1.f / (1.f + __expf(-s1));
    }
    {
        float t = cv.y * scale + shift;
        float s1 = 1.f / (1.f + __expf(-t));
        g.y = 1.f / (1.f + __expf(-s1));
    }
    {
        float t = cv.z * scale + shift;
        float s1 = 1.f / (1.f + __expf(-t));
        g.z = 1.f / (1.f + __expf(-s1));
    }
    {
        float t = cv.w * scale + shift;
        float s1 = 1.f / (1.f + __expf(-t));
        g.w = 1.f / (1.f + __expf(-s1));
    }

    const float4* x4 = (const float4*)x + (size_t)(n * CC + cblk * 32) * QPP + hwq;
    v4f* o4 = (v4f*)out + (size_t)(n * CC + cblk * 32) * QPP + hwq;
#pragma unroll 8
    for (int i = 0; i < 32; ++i) {
        float4 xv = x4[(size_t)i * QPP];
        v4f r;
        r.x = xv.x * g.x; r.y = xv.y * g.y;
        r.z = xv.z * g.z; r.w = xv.w * g.w;
        __builtin_nontemporal_store(r, &o4[(size_t)i * QPP]);
    }
}

extern "C" void kernel_launch(void* const* d_in, const int* in_sizes, int n_in,
                              void* d_out, int out_size, void* d_ws, size_t ws_size,
                              hipStream_t stream) {
    const float* x = (const float*)d_in[0];
    const float* cw = (const float*)d_in[1];
    const float* gamma = (const float*)d_in[2];
    const float* beta = (const float*)d_in[3];
    float* out = (float*)d_out;

    float* ws = (float*)d_ws;
    float* pmaxp = ws;                          // NGRP*NQ float4
    float* psump = pmaxp + (size_t)NGRP * NQ * 4;
    float* pool = psump + (size_t)NGRP * NQ * 4; // 2*NHW floats
    float* conv = pool + 2 * NHW;                // NHW floats
    float* stats = conv + NHW;                   // 2 floats

    k_pool_lin<<<NGRP * NQ / 256, 256, 0, stream>>>(x, pmaxp, psump, stats);
    k_merge<<<98, 256, 0, stream>>>(pmaxp, psump, pool);
    k_conv<<<392, 256, 0, stream>>>(pool, cw, conv, stats);
    k_apply<<<NN * ABLK * QPP / 256, 256, 0, stream>>>(x, conv, stats, gamma,
                                                       beta, out);
}